// Round 7
// baseline (83.042 us; speedup 1.0000x reference)
//
#include <hip/hip_runtime.h>
#include <math.h>

// Problem constants: N=8192 nodes, IN=512, OUT=8192, HEADS=1.
#define NN    8192
#define INC   512
#define NCOPY 16     // exclusive histogram copies (= hist blocks)

// ws float offsets. NOTHING needs pre-zeroing: every slot is exact-written.
#define OFF_DEGP 0                        // [16][NN]  deg partial histograms
#define OFF_ADVP (16 * NN)                // [16][NN]  adv partial histograms
#define OFF_UP   (32 * NN)                // [128][512] u partials
#define OFF_TP   (32 * NN + 128 * INC)    // [128][512] t partials
#define OFF_SP   (32 * NN + 256 * INC)    // [16][NN]  s partials (per c-chunk)
#define OFF_S1P  (48 * NN + 256 * INC)    // [128]     scal1 block partials
#define OFF_XU   (48 * NN + 256 * INC + 128)  // [NN]
#define OFF_C0   (49 * NN + 256 * INC + 128)  // [8]

// ---------------------------------------------------------------------------
// N1: blocks 0..15   -> deg LDS-histogram, exclusive copy b (exact store out)
//     blocks 16..143 -> u partials: u_parts[b-16][c] = sum of 64 rows of
//                       att[r]*lin_w[r,c]  (no atomics)
//     block  144     -> c0 = lin_b . a1  -> ws[OFF_C0]
__global__ __launch_bounds__(1024) void n1_deg_u_c0(
        const float* __restrict__ lin_w, const float* __restrict__ att,
        const float* __restrict__ lin_b, const int* __restrict__ row,
        int E, float* __restrict__ ws) {
    __shared__ float smem[8192];          // 32 KB, reused per branch
    const int b = blockIdx.x, tid = threadIdx.x;

    if (b < NCOPY) {                      // ---- deg histogram ----
        #pragma unroll
        for (int m = 0; m < 8; ++m) smem[tid + m * 1024] = 0.f;
        __syncthreads();
        const int per = (E + NCOPY - 1) / NCOPY;
        const int e0 = b * per;
        const int e1 = (e0 + per < E) ? e0 + per : E;
        for (int i = e0 + tid * 4; i + 3 < e1; i += 4096) {
            int4 r = *(const int4*)(row + i);
            atomicAdd(&smem[r.x], 1.f); atomicAdd(&smem[r.y], 1.f);
            atomicAdd(&smem[r.z], 1.f); atomicAdd(&smem[r.w], 1.f);
        }
        for (int e = e0 + ((e1 - e0) & ~3) + tid; e < e1; e += 1024)
            atomicAdd(&smem[row[e]], 1.f);
        __syncthreads();
        float4* dst = (float4*)(ws + OFF_DEGP + (size_t)b * NN);
        dst[tid]        = ((float4*)smem)[tid];
        dst[tid + 1024] = ((float4*)smem)[tid + 1024];
    } else if (b < 16 + 128) {            // ---- u partials ----
        float4* lds4 = (float4*)smem;     // [1024] f4 view (16 KB < 32 KB)
        const int r0 = (b - 16) * 64;
        const int c4 = tid & 127, rg = tid >> 7;
        float4 acc = {0.f, 0.f, 0.f, 0.f};
        #pragma unroll
        for (int it = 0; it < 8; ++it) {
            int r = r0 + rg * 8 + it;
            float w = att[r];
            float4 v = ((const float4*)(lin_w + (size_t)r * INC))[c4];
            acc.x += w * v.x; acc.y += w * v.y; acc.z += w * v.z; acc.w += w * v.w;
        }
        lds4[tid] = acc;
        __syncthreads();
        #pragma unroll
        for (int off = 4; off > 0; off >>= 1) {
            if (rg < off) {
                float4 o = lds4[(rg + off) * 128 + c4];
                float4 m = lds4[tid];
                m.x += o.x; m.y += o.y; m.z += o.z; m.w += o.w;
                lds4[tid] = m;
            }
            __syncthreads();
        }
        if (rg == 0)
            ((float4*)(ws + OFF_UP + (size_t)(b - 16) * INC))[c4] = lds4[c4];
    } else {                              // ---- c0 ----
        float v = 0.f;
        for (int i = tid; i < NN; i += 1024) v += lin_b[i] * att[i];
        smem[tid] = v;
        __syncthreads();
        #pragma unroll
        for (int off = 512; off > 0; off >>= 1) {
            if (tid < off) smem[tid] += smem[tid + off];
            __syncthreads();
        }
        if (tid == 0) ws[OFF_C0] = smem[0];
    }
}

// ---------------------------------------------------------------------------
// N2: blocks 0..15   -> adv LDS-histogram, exclusive copy b: rebuild the FULL
//                       dinv vector in LDS (sum of 16 deg partials + rsqrt),
//                       then per-edge gather is LDS-only. Exact store out.
//     blocks 16..143 -> fused single pass over x (64 rows each):
//                       t_parts[b-16][c] = sum dinv[r]*x[r,c]  (dinv inline)
//                       xu[r] = x[r,:] . u   (u rebuilt from 128 partials)
__global__ __launch_bounds__(1024) void n2_adv_t_xu(
        const float* __restrict__ x, const int* __restrict__ row,
        const int* __restrict__ col, int E, float* __restrict__ ws) {
    __shared__ float smem[16384];         // 64 KB, reused per branch
    const int b = blockIdx.x, tid = threadIdx.x;
    const float* __restrict__ degp = ws + OFF_DEGP;

    if (b < NCOPY) {                      // ---- adv histogram ----
        float* dl = smem;                 // dinv [8192]
        float* al = smem + 8192;          // adv  [8192]
        #pragma unroll
        for (int m = 0; m < 8; ++m) {
            int i = tid + m * 1024;
            float d = 0.f;
            #pragma unroll
            for (int k = 0; k < NCOPY; ++k) d += degp[k * NN + i];
            dl[i] = 1.f / sqrtf(d);
            al[i] = 0.f;
        }
        __syncthreads();
        const int per = (E + NCOPY - 1) / NCOPY;
        const int e0 = b * per;
        const int e1 = (e0 + per < E) ? e0 + per : E;
        for (int i = e0 + tid * 4; i + 3 < e1; i += 4096) {
            int4 r = *(const int4*)(row + i);
            int4 c = *(const int4*)(col + i);
            atomicAdd(&al[r.x], dl[c.x]); atomicAdd(&al[r.y], dl[c.y]);
            atomicAdd(&al[r.z], dl[c.z]); atomicAdd(&al[r.w], dl[c.w]);
        }
        for (int e = e0 + ((e1 - e0) & ~3) + tid; e < e1; e += 1024)
            atomicAdd(&al[row[e]], dl[col[e]]);
        __syncthreads();
        float4* dst = (float4*)(ws + OFF_ADVP + (size_t)b * NN);
        dst[tid]        = ((float4*)al)[tid];
        dst[tid + 1024] = ((float4*)al)[tid + 1024];
    } else {                              // ---- fused t + xu pass over x ----
        float4* lds4   = (float4*)smem;            // floats     0..4095
        float4* ured   = (float4*)(smem + 4096);   // floats  4096..8191
        float4* u4     = (float4*)(smem + 8192);   // floats  8192..8703
        float*  dinv_l = smem + 8704;              // [64]
        float*  xured  = smem + 8768;              // [8*8*2 = 128]
        const int r0 = (b - NCOPY) * 64;
        const int c4 = tid & 127, grp = tid >> 7;

        // u = sum of 128 u_parts (each thread: 16 copies of its f4 column)
        {
            const float4* up = (const float4*)(ws + OFF_UP);
            float4 a = {0.f, 0.f, 0.f, 0.f};
            #pragma unroll
            for (int q = 0; q < 16; ++q) {
                float4 v = up[(grp + q * 8) * 128 + c4];
                a.x += v.x; a.y += v.y; a.z += v.z; a.w += v.w;
            }
            ured[grp * 128 + c4] = a;
        }
        if (tid < 64) {                   // dinv for this block's 64 rows
            float d = 0.f;
            #pragma unroll
            for (int k = 0; k < NCOPY; ++k) d += degp[k * NN + r0 + tid];
            dinv_l[tid] = 1.f / sqrtf(d);
        }
        __syncthreads();
        if (tid < 128) {
            float4 a = {0.f, 0.f, 0.f, 0.f};
            #pragma unroll
            for (int g = 0; g < 8; ++g) {
                float4 v = ured[g * 128 + tid];
                a.x += v.x; a.y += v.y; a.z += v.z; a.w += v.w;
            }
            u4[tid] = a;
        }
        __syncthreads();

        const int lane = tid & 63;
        float4 accT = {0.f, 0.f, 0.f, 0.f};
        float xup[8];
        #pragma unroll
        for (int it = 0; it < 8; ++it) {
            int rl = grp + it * 8;
            float4 v = ((const float4*)(x + (size_t)(r0 + rl) * INC))[c4];
            float w = dinv_l[rl];
            accT.x += w * v.x; accT.y += w * v.y; accT.z += w * v.z; accT.w += w * v.w;
            float4 uu = u4[c4];
            xup[it] = v.x * uu.x + v.y * uu.y + v.z * uu.z + v.w * uu.w;
        }
        #pragma unroll
        for (int it = 0; it < 8; ++it) {
            float a = xup[it];
            #pragma unroll
            for (int off = 32; off > 0; off >>= 1) a += __shfl_down(a, off);
            if (lane == 0) xured[grp * 16 + it * 2 + ((tid >> 6) & 1)] = a;
        }
        lds4[tid] = accT;
        __syncthreads();
        if (tid < 64) {
            int rg2 = tid >> 3, it2 = tid & 7;
            ws[OFF_XU + r0 + rg2 + it2 * 8] =
                xured[rg2 * 16 + it2 * 2] + xured[rg2 * 16 + it2 * 2 + 1];
        }
        #pragma unroll
        for (int off = 4; off > 0; off >>= 1) {
            if (grp < off) {
                float4 o = lds4[(grp + off) * 128 + c4];
                float4 m = lds4[tid];
                m.x += o.x; m.y += o.y; m.z += o.z; m.w += o.w;
                lds4[tid] = m;
            }
            __syncthreads();
        }
        if (grp == 0)
            ((float4*)(ws + OFF_TP + (size_t)(b - NCOPY) * INC))[c4] = lds4[c4];
    }
}

// ---------------------------------------------------------------------------
// N3 (128 blocks = 16 c-chunks x 8 k-chunks): exact-write s partials.
//   block (cb,kb): s_parts[cb][kbase+k] = sum_{c in cb's 32 cols} t[c]*W[c,k]
//   t rebuilt from the 128 t_parts for just this block's 32 columns.
//   Also scal1 block partial (dot with a2) -> ws[OFF_S1P + b]. No atomics.
__global__ __launch_bounds__(1024) void n3_s(
        const float* __restrict__ weight, const float* __restrict__ att,
        float* __restrict__ ws) {
    __shared__ float4 red4[1024];
    __shared__ float tred[32][33];
    __shared__ float tl[32];
    __shared__ float wred[4];
    const int b = blockIdx.x, tid = threadIdx.x;
    const int cb = b >> 3, kb = b & 7;
    const int cbase = cb * 32, kbase = kb * 1024;

    {   // t slice: sum 128 partial copies for 32 columns
        const int cc = tid & 31, p = tid >> 5;     // p in 0..31
        const float* tp = ws + OFF_TP;
        float v = 0.f;
        #pragma unroll
        for (int q = 0; q < 4; ++q) v += tp[(p + q * 32) * INC + cbase + cc];
        tred[cc][p] = v;
    }
    __syncthreads();
    if (tid < 32) {
        float v = 0.f;
        #pragma unroll
        for (int j = 0; j < 32; ++j) v += tred[tid][j];
        tl[tid] = v;
    }
    __syncthreads();

    const int k4 = tid & 255, csub = tid >> 8;     // 4 csub groups x 8 cols
    float4 acc = {0.f, 0.f, 0.f, 0.f};
    #pragma unroll
    for (int cl = 0; cl < 8; ++cl) {
        int c = csub * 8 + cl;
        float tc = tl[c];
        float4 v = *(const float4*)(weight + (size_t)(cbase + c) * NN + kbase + k4 * 4);
        acc.x += tc * v.x; acc.y += tc * v.y; acc.z += tc * v.z; acc.w += tc * v.w;
    }
    red4[tid] = acc;
    __syncthreads();
    float p1 = 0.f;
    if (csub == 0) {
        float4 a = red4[tid];
        float4 o1 = red4[tid + 256], o2 = red4[tid + 512], o3 = red4[tid + 768];
        a.x += o1.x + o2.x + o3.x; a.y += o1.y + o2.y + o3.y;
        a.z += o1.z + o2.z + o3.z; a.w += o1.w + o2.w + o3.w;
        *(float4*)(ws + OFF_SP + (size_t)cb * NN + kbase + k4 * 4) = a;
        float4 a2 = *(const float4*)(att + NN + kbase + k4 * 4);
        p1 = a.x * a2.x + a.y * a2.y + a.z * a2.z + a.w * a2.w;
    }
    #pragma unroll
    for (int off = 32; off > 0; off >>= 1) p1 += __shfl_down(p1, off);
    if (csub == 0 && (tid & 63) == 0) wred[tid >> 6] = p1;
    __syncthreads();
    if (tid == 0) ws[OFF_S1P + b] = wred[0] + wred[1] + wred[2] + wred[3];
}

// ---------------------------------------------------------------------------
// N4 (single block): scal1 = sum(s1 parts); per i: adv = sum16 adv_parts,
//   s = sum16 s_parts, alpha = leaky_relu(xu + c0 + adv*scal1);
//   scal2 = dot(s, alpha); out = relu(adv*scal2 + bias). All float4, 8 i/thread.
__global__ __launch_bounds__(1024) void n4_final(
        const float* __restrict__ bias, const float* __restrict__ ws,
        float* __restrict__ out) {
    __shared__ float red[1024];
    const int tid = threadIdx.x;

    red[tid] = (tid < 128) ? ws[OFF_S1P + tid] : 0.f;
    __syncthreads();
    #pragma unroll
    for (int off = 512; off > 0; off >>= 1) {
        if (tid < off) red[tid] += red[tid + off];
        __syncthreads();
    }
    const float scal1 = red[0];
    const float c0 = ws[OFF_C0];
    __syncthreads();

    const float4* advp = (const float4*)(ws + OFF_ADVP);
    const float4* sp   = (const float4*)(ws + OFF_SP);
    float4 adv0 = {0.f,0.f,0.f,0.f}, adv1 = {0.f,0.f,0.f,0.f};
    float4 sv0  = {0.f,0.f,0.f,0.f}, sv1  = {0.f,0.f,0.f,0.f};
    #pragma unroll
    for (int k = 0; k < NCOPY; ++k) {
        float4 a = advp[k * 2048 + tid * 2], a2 = advp[k * 2048 + tid * 2 + 1];
        adv0.x += a.x;  adv0.y += a.y;  adv0.z += a.z;  adv0.w += a.w;
        adv1.x += a2.x; adv1.y += a2.y; adv1.z += a2.z; adv1.w += a2.w;
        float4 s = sp[k * 2048 + tid * 2], s2 = sp[k * 2048 + tid * 2 + 1];
        sv0.x += s.x;  sv0.y += s.y;  sv0.z += s.z;  sv0.w += s.w;
        sv1.x += s2.x; sv1.y += s2.y; sv1.z += s2.z; sv1.w += s2.w;
    }
    float4 xu0 = ((const float4*)(ws + OFF_XU))[tid * 2];
    float4 xu1 = ((const float4*)(ws + OFF_XU))[tid * 2 + 1];

    float av[8] = {adv0.x, adv0.y, adv0.z, adv0.w, adv1.x, adv1.y, adv1.z, adv1.w};
    float xv[8] = {xu0.x, xu0.y, xu0.z, xu0.w, xu1.x, xu1.y, xu1.z, xu1.w};
    float sv[8] = {sv0.x, sv0.y, sv0.z, sv0.w, sv1.x, sv1.y, sv1.z, sv1.w};
    float acc = 0.f;
    #pragma unroll
    for (int j = 0; j < 8; ++j) {
        float a = xv[j] + c0 + av[j] * scal1;
        float lr = a > 0.f ? a : 0.2f * a;
        acc += lr * sv[j];
    }
    red[tid] = acc;
    __syncthreads();
    #pragma unroll
    for (int off = 512; off > 0; off >>= 1) {
        if (tid < off) red[tid] += red[tid + off];
        __syncthreads();
    }
    const float scal2 = red[0];

    float4 b0 = ((const float4*)bias)[tid * 2], b1 = ((const float4*)bias)[tid * 2 + 1];
    float4 o0, o1;
    o0.x = fmaxf(av[0] * scal2 + b0.x, 0.f); o0.y = fmaxf(av[1] * scal2 + b0.y, 0.f);
    o0.z = fmaxf(av[2] * scal2 + b0.z, 0.f); o0.w = fmaxf(av[3] * scal2 + b0.w, 0.f);
    o1.x = fmaxf(av[4] * scal2 + b1.x, 0.f); o1.y = fmaxf(av[5] * scal2 + b1.y, 0.f);
    o1.z = fmaxf(av[6] * scal2 + b1.z, 0.f); o1.w = fmaxf(av[7] * scal2 + b1.w, 0.f);
    ((float4*)out)[tid * 2]     = o0;
    ((float4*)out)[tid * 2 + 1] = o1;
}

// ---------------------------------------------------------------------------
extern "C" void kernel_launch(void* const* d_in, const int* in_sizes, int n_in,
                              void* d_out, int out_size, void* d_ws, size_t ws_size,
                              hipStream_t stream) {
    const float* x      = (const float*)d_in[0];   // [8192, 512]
    const int*   eidx   = (const int*)d_in[1];     // [2, E]
    const float* weight = (const float*)d_in[2];   // [512, 8192]
    const float* bias   = (const float*)d_in[3];   // [8192]
    const float* att    = (const float*)d_in[4];   // [16384]
    const float* lin_w  = (const float*)d_in[5];   // [8192, 512]
    const float* lin_b  = (const float*)d_in[6];   // [8192]

    const int E = in_sizes[1] / 2;
    const int* row = eidx;
    const int* col = eidx + E;
    float* ws  = (float*)d_ws;
    float* out = (float*)d_out;

    n1_deg_u_c0<<<145, 1024, 0, stream>>>(lin_w, att, lin_b, row, E, ws);
    n2_adv_t_xu<<<144, 1024, 0, stream>>>(x, row, col, E, ws);
    n3_s       <<<128, 1024, 0, stream>>>(weight, att, ws);
    n4_final   <<<1,   1024, 0, stream>>>(bias, ws, out);
}